// Round 1
// baseline (1494.887 us; speedup 1.0000x reference)
//
#include <hip/hip_runtime.h>
#include <hip/hip_bf16.h>
#include <stdint.h>

// GeneralConv fused pipeline for MI355X (gfx950).
// Needs ws_size >= ~26.4 MB: sums (N*128 f32) + counts (N f32) + bf16 packed weights.

#define NN 50000
#define NE 800000

typedef short bf16x8 __attribute__((ext_vector_type(8)));
typedef float f32x4 __attribute__((ext_vector_type(4)));

#define MFMA16(a, b, c) __builtin_amdgcn_mfma_f32_16x16x32_bf16((a), (b), (c), 0, 0, 0)

__device__ __forceinline__ unsigned short f2bf(float f) {
  union { float f; uint32_t u; } x; x.f = f;
  uint32_t u = x.u;
  u += 0x7FFFu + ((u >> 16) & 1u);   // RNE
  return (unsigned short)(u >> 16);
}
__device__ __forceinline__ float sigm(float x) { return 1.0f / (1.0f + __expf(-x)); }

// Transpose fp32 W[K][128] -> bf16 WT[128][Kpad], zero-padded rows k>=K.
__global__ void pack_wT(const float* __restrict__ W, unsigned short* __restrict__ WT,
                        int K, int Kpad) {
  int id = blockIdx.x * 256 + threadIdx.x;
  if (id >= 128 * Kpad) return;
  int h = id / Kpad, k = id - h * Kpad;
  WT[id] = f2bf(k < K ? W[k * 128 + h] : 0.0f);
}

// ---------------------------------------------------------------------------
// bond: per block 128 edges. x_e = [inp[src] | inp[dst] | edge_feat] (K=384).
// GatedMLP -> atomic scatter-add into sums[N][128]; counts[N] += 1 per edge.
// LDS: phase1 A@0(16K) Bm@16K Bg@32K ; phase2 HID@0(32K) W2@32K(32K)
// ---------------------------------------------------------------------------
__global__ __launch_bounds__(256) void bond_kernel(
    const float* __restrict__ node_inp, const float* __restrict__ edge_feat,
    const int* __restrict__ ei,
    const unsigned short* __restrict__ Wm0T, const unsigned short* __restrict__ Wg0T,
    const unsigned short* __restrict__ Wm1T, const unsigned short* __restrict__ Wg1T,
    const float* __restrict__ bm0, const float* __restrict__ bg0,
    const float* __restrict__ bm1, const float* __restrict__ bg1,
    float* __restrict__ sums, float* __restrict__ counts) {
  __shared__ char smem[65536];
  const int t = threadIdx.x;
  const int e0 = blockIdx.x * 128;
  const int lane = t & 63;
  const int wv = t >> 6;
  const int lg = lane >> 4;
  const int lr = lane & 15;

  if (t < 128) atomicAdd(&counts[ei[e0 + t]], 1.0f);

  f32x4 accm[2][8] = {};
  f32x4 accg[2][8] = {};

  for (int c = 0; c < 6; ++c) {
    __syncthreads();
    // stage A chunk [128 rows][64 k] bf16, XOR-swizzled 16B granules
#pragma unroll
    for (int it = 0; it < 4; ++it) {
      int q = it * 256 + t;
      int row = q >> 3, slot = q & 7;
      int e = e0 + row;
      const float* sp;
      if (c < 2)      sp = node_inp + (size_t)ei[e] * 128 + c * 64;
      else if (c < 4) sp = node_inp + (size_t)ei[NE + e] * 128 + (c - 2) * 64;
      else            sp = edge_feat + (size_t)e * 128 + (c - 4) * 64;
      float4 va = ((const float4*)sp)[slot * 2];
      float4 vb = ((const float4*)sp)[slot * 2 + 1];
      uint4 pk;
      pk.x = (uint32_t)f2bf(va.x) | ((uint32_t)f2bf(va.y) << 16);
      pk.y = (uint32_t)f2bf(va.z) | ((uint32_t)f2bf(va.w) << 16);
      pk.z = (uint32_t)f2bf(vb.x) | ((uint32_t)f2bf(vb.y) << 16);
      pk.w = (uint32_t)f2bf(vb.z) | ((uint32_t)f2bf(vb.w) << 16);
      *(uint4*)(smem + ((row * 128 + slot * 16) ^ ((row & 7) << 4))) = pk;
    }
    // stage B chunks (already bf16, [col][64 k], same swizzle)
#pragma unroll
    for (int it = 0; it < 4; ++it) {
      int q = it * 256 + t;
      int col = q >> 3, slot = q & 7;
      int off = (col * 128 + slot * 16) ^ ((col & 7) << 4);
      *(uint4*)(smem + 16384 + off) = *(const uint4*)(Wm0T + col * 384 + c * 64 + slot * 8);
      *(uint4*)(smem + 32768 + off) = *(const uint4*)(Wg0T + col * 384 + c * 64 + slot * 8);
    }
    __syncthreads();
#pragma unroll
    for (int ks = 0; ks < 2; ++ks) {
      int k2 = (ks * 32 + lg * 8) * 2;
      int r0 = wv * 32 + lr;
      bf16x8 a0 = *(const bf16x8*)(smem + ((r0 * 128 + k2) ^ ((r0 & 7) << 4)));
      bf16x8 a1 = *(const bf16x8*)(smem + (((r0 + 16) * 128 + k2) ^ ((r0 & 7) << 4)));
#pragma unroll
      for (int nf = 0; nf < 8; ++nf) {
        int col = nf * 16 + lr;
        int boff = (col * 128 + k2) ^ ((col & 7) << 4);
        bf16x8 bm = *(const bf16x8*)(smem + 16384 + boff);
        accm[0][nf] = MFMA16(a0, bm, accm[0][nf]);
        accm[1][nf] = MFMA16(a1, bm, accm[1][nf]);
        bf16x8 bg = *(const bf16x8*)(smem + 32768 + boff);
        accg[0][nf] = MFMA16(a0, bg, accg[0][nf]);
        accg[1][nf] = MFMA16(a1, bg, accg[1][nf]);
      }
    }
  }

  // ---- phase 2, branch m: silu(hid) -> LDS, W2 -> LDS, layer-2 MFMA ----
  float b0r[8];
#pragma unroll
  for (int nf = 0; nf < 8; ++nf) b0r[nf] = bm0[nf * 16 + lr];
  __syncthreads();
#pragma unroll
  for (int mf = 0; mf < 2; ++mf)
#pragma unroll
    for (int nf = 0; nf < 8; ++nf)
#pragma unroll
      for (int r = 0; r < 4; ++r) {
        float h = accm[mf][nf][r] + b0r[nf];
        h = h * sigm(h);
        int row = wv * 32 + mf * 16 + lg * 4 + r;
        int col = nf * 16 + lr;
        *(unsigned short*)(smem + ((row * 256 + col * 2) ^ ((row & 7) << 4))) = f2bf(h);
      }
#pragma unroll
  for (int it = 0; it < 8; ++it) {
    int q = it * 256 + t;
    int col = q >> 4, slot = q & 15;
    *(uint4*)(smem + 32768 + ((col * 256 + slot * 16) ^ ((col & 7) << 4))) =
        *(const uint4*)(Wm1T + col * 128 + slot * 8);
  }
  __syncthreads();
  f32x4 acc2m[2][8] = {};
#pragma unroll
  for (int ks = 0; ks < 4; ++ks) {
    int k2 = (ks * 32 + lg * 8) * 2;
    int r0 = wv * 32 + lr;
    bf16x8 a0 = *(const bf16x8*)(smem + ((r0 * 256 + k2) ^ ((r0 & 7) << 4)));
    bf16x8 a1 = *(const bf16x8*)(smem + (((r0 + 16) * 256 + k2) ^ ((r0 & 7) << 4)));
#pragma unroll
    for (int nf = 0; nf < 8; ++nf) {
      int col = nf * 16 + lr;
      bf16x8 b = *(const bf16x8*)(smem + 32768 + ((col * 256 + k2) ^ ((col & 7) << 4)));
      acc2m[0][nf] = MFMA16(a0, b, acc2m[0][nf]);
      acc2m[1][nf] = MFMA16(a1, b, acc2m[1][nf]);
    }
  }

  // ---- phase 2, branch g ----
  __syncthreads();
#pragma unroll
  for (int nf = 0; nf < 8; ++nf) b0r[nf] = bg0[nf * 16 + lr];
#pragma unroll
  for (int mf = 0; mf < 2; ++mf)
#pragma unroll
    for (int nf = 0; nf < 8; ++nf)
#pragma unroll
      for (int r = 0; r < 4; ++r) {
        float h = accg[mf][nf][r] + b0r[nf];
        h = h * sigm(h);
        int row = wv * 32 + mf * 16 + lg * 4 + r;
        int col = nf * 16 + lr;
        *(unsigned short*)(smem + ((row * 256 + col * 2) ^ ((row & 7) << 4))) = f2bf(h);
      }
#pragma unroll
  for (int it = 0; it < 8; ++it) {
    int q = it * 256 + t;
    int col = q >> 4, slot = q & 15;
    *(uint4*)(smem + 32768 + ((col * 256 + slot * 16) ^ ((col & 7) << 4))) =
        *(const uint4*)(Wg1T + col * 128 + slot * 8);
  }
  __syncthreads();
  f32x4 acc2g[2][8] = {};
#pragma unroll
  for (int ks = 0; ks < 4; ++ks) {
    int k2 = (ks * 32 + lg * 8) * 2;
    int r0 = wv * 32 + lr;
    bf16x8 a0 = *(const bf16x8*)(smem + ((r0 * 256 + k2) ^ ((r0 & 7) << 4)));
    bf16x8 a1 = *(const bf16x8*)(smem + (((r0 + 16) * 256 + k2) ^ ((r0 & 7) << 4)));
#pragma unroll
    for (int nf = 0; nf < 8; ++nf) {
      int col = nf * 16 + lr;
      bf16x8 b = *(const bf16x8*)(smem + 32768 + ((col * 256 + k2) ^ ((col & 7) << 4)));
      acc2g[0][nf] = MFMA16(a0, b, acc2g[0][nf]);
      acc2g[1][nf] = MFMA16(a1, b, acc2g[1][nf]);
    }
  }

  // ---- combine m * sigmoid(g), atomic scatter by src ----
  float bm1r[8], bg1r[8];
#pragma unroll
  for (int nf = 0; nf < 8; ++nf) {
    bm1r[nf] = bm1[nf * 16 + lr];
    bg1r[nf] = bg1[nf * 16 + lr];
  }
#pragma unroll
  for (int mf = 0; mf < 2; ++mf)
#pragma unroll
    for (int r = 0; r < 4; ++r) {
      int row = wv * 32 + mf * 16 + lg * 4 + r;
      int s = ei[e0 + row];
      float* dp = sums + (size_t)s * 128;
#pragma unroll
      for (int nf = 0; nf < 8; ++nf) {
        float mv = acc2m[mf][nf][r] + bm1r[nf];
        float gv = sigm(acc2g[mf][nf][r] + bg1r[nf]);
        atomicAdd(dp + nf * 16 + lr, mv * gv);
      }
    }
}

// ---------------------------------------------------------------------------
// node: per block 128 nodes. x_n = [inp | sums/counts | coords | gs] (K=385->448)
// GatedMLP -> LayerNorm -> out
// ---------------------------------------------------------------------------
__global__ __launch_bounds__(256) void node_kernel(
    const float* __restrict__ node_inp, const float* __restrict__ coords,
    const float* __restrict__ gstate,
    const float* __restrict__ sums, const float* __restrict__ counts,
    const unsigned short* __restrict__ Wm0T, const unsigned short* __restrict__ Wg0T,
    const unsigned short* __restrict__ Wm1T, const unsigned short* __restrict__ Wg1T,
    const float* __restrict__ bm0, const float* __restrict__ bg0,
    const float* __restrict__ bm1, const float* __restrict__ bg1,
    const float* __restrict__ gamma, const float* __restrict__ beta,
    float* __restrict__ out) {
  __shared__ char smem[65536];
  const int t = threadIdx.x;
  const int n0 = blockIdx.x * 128;
  const int lane = t & 63;
  const int wv = t >> 6;
  const int lg = lane >> 4;
  const int lr = lane & 15;

  f32x4 accm[2][8] = {};
  f32x4 accg[2][8] = {};

  for (int c = 0; c < 7; ++c) {
    __syncthreads();
#pragma unroll
    for (int it = 0; it < 4; ++it) {
      int q = it * 256 + t;
      int row = q >> 3, slot = q & 7;
      int rg = n0 + row;
      float4 va = make_float4(0.f, 0.f, 0.f, 0.f);
      float4 vb = make_float4(0.f, 0.f, 0.f, 0.f);
      if (rg < NN) {
        if (c < 2) {
          const float4* p = (const float4*)(node_inp + (size_t)rg * 128 + c * 64);
          va = p[slot * 2]; vb = p[slot * 2 + 1];
        } else if (c < 4) {
          float cnt = counts[rg];
          float inv = cnt > 0.f ? 1.f / cnt : 0.f;
          const float4* p = (const float4*)(sums + (size_t)rg * 128 + (c - 2) * 64);
          va = p[slot * 2]; vb = p[slot * 2 + 1];
          va.x *= inv; va.y *= inv; va.z *= inv; va.w *= inv;
          vb.x *= inv; vb.y *= inv; vb.z *= inv; vb.w *= inv;
        } else if (c < 6) {
          const float4* p = (const float4*)(coords + (size_t)rg * 128 + (c - 4) * 64);
          va = p[slot * 2]; vb = p[slot * 2 + 1];
        } else {
          if (slot == 0) va.x = gstate[rg];  // k=384 -> gs, rest zero pad
        }
      }
      uint4 pk;
      pk.x = (uint32_t)f2bf(va.x) | ((uint32_t)f2bf(va.y) << 16);
      pk.y = (uint32_t)f2bf(va.z) | ((uint32_t)f2bf(va.w) << 16);
      pk.z = (uint32_t)f2bf(vb.x) | ((uint32_t)f2bf(vb.y) << 16);
      pk.w = (uint32_t)f2bf(vb.z) | ((uint32_t)f2bf(vb.w) << 16);
      *(uint4*)(smem + ((row * 128 + slot * 16) ^ ((row & 7) << 4))) = pk;
    }
#pragma unroll
    for (int it = 0; it < 4; ++it) {
      int q = it * 256 + t;
      int col = q >> 3, slot = q & 7;
      int off = (col * 128 + slot * 16) ^ ((col & 7) << 4);
      *(uint4*)(smem + 16384 + off) = *(const uint4*)(Wm0T + col * 448 + c * 64 + slot * 8);
      *(uint4*)(smem + 32768 + off) = *(const uint4*)(Wg0T + col * 448 + c * 64 + slot * 8);
    }
    __syncthreads();
#pragma unroll
    for (int ks = 0; ks < 2; ++ks) {
      int k2 = (ks * 32 + lg * 8) * 2;
      int r0 = wv * 32 + lr;
      bf16x8 a0 = *(const bf16x8*)(smem + ((r0 * 128 + k2) ^ ((r0 & 7) << 4)));
      bf16x8 a1 = *(const bf16x8*)(smem + (((r0 + 16) * 128 + k2) ^ ((r0 & 7) << 4)));
#pragma unroll
      for (int nf = 0; nf < 8; ++nf) {
        int col = nf * 16 + lr;
        int boff = (col * 128 + k2) ^ ((col & 7) << 4);
        bf16x8 bm = *(const bf16x8*)(smem + 16384 + boff);
        accm[0][nf] = MFMA16(a0, bm, accm[0][nf]);
        accm[1][nf] = MFMA16(a1, bm, accm[1][nf]);
        bf16x8 bg = *(const bf16x8*)(smem + 32768 + boff);
        accg[0][nf] = MFMA16(a0, bg, accg[0][nf]);
        accg[1][nf] = MFMA16(a1, bg, accg[1][nf]);
      }
    }
  }

  // ---- phase 2, branch m ----
  float b0r[8];
#pragma unroll
  for (int nf = 0; nf < 8; ++nf) b0r[nf] = bm0[nf * 16 + lr];
  __syncthreads();
#pragma unroll
  for (int mf = 0; mf < 2; ++mf)
#pragma unroll
    for (int nf = 0; nf < 8; ++nf)
#pragma unroll
      for (int r = 0; r < 4; ++r) {
        float h = accm[mf][nf][r] + b0r[nf];
        h = h * sigm(h);
        int row = wv * 32 + mf * 16 + lg * 4 + r;
        int col = nf * 16 + lr;
        *(unsigned short*)(smem + ((row * 256 + col * 2) ^ ((row & 7) << 4))) = f2bf(h);
      }
#pragma unroll
  for (int it = 0; it < 8; ++it) {
    int q = it * 256 + t;
    int col = q >> 4, slot = q & 15;
    *(uint4*)(smem + 32768 + ((col * 256 + slot * 16) ^ ((col & 7) << 4))) =
        *(const uint4*)(Wm1T + col * 128 + slot * 8);
  }
  __syncthreads();
  f32x4 acc2m[2][8] = {};
#pragma unroll
  for (int ks = 0; ks < 4; ++ks) {
    int k2 = (ks * 32 + lg * 8) * 2;
    int r0 = wv * 32 + lr;
    bf16x8 a0 = *(const bf16x8*)(smem + ((r0 * 256 + k2) ^ ((r0 & 7) << 4)));
    bf16x8 a1 = *(const bf16x8*)(smem + (((r0 + 16) * 256 + k2) ^ ((r0 & 7) << 4)));
#pragma unroll
    for (int nf = 0; nf < 8; ++nf) {
      int col = nf * 16 + lr;
      bf16x8 b = *(const bf16x8*)(smem + 32768 + ((col * 256 + k2) ^ ((col & 7) << 4)));
      acc2m[0][nf] = MFMA16(a0, b, acc2m[0][nf]);
      acc2m[1][nf] = MFMA16(a1, b, acc2m[1][nf]);
    }
  }

  // ---- phase 2, branch g ----
  __syncthreads();
#pragma unroll
  for (int nf = 0; nf < 8; ++nf) b0r[nf] = bg0[nf * 16 + lr];
#pragma unroll
  for (int mf = 0; mf < 2; ++mf)
#pragma unroll
    for (int nf = 0; nf < 8; ++nf)
#pragma unroll
      for (int r = 0; r < 4; ++r) {
        float h = accg[mf][nf][r] + b0r[nf];
        h = h * sigm(h);
        int row = wv * 32 + mf * 16 + lg * 4 + r;
        int col = nf * 16 + lr;
        *(unsigned short*)(smem + ((row * 256 + col * 2) ^ ((row & 7) << 4))) = f2bf(h);
      }
#pragma unroll
  for (int it = 0; it < 8; ++it) {
    int q = it * 256 + t;
    int col = q >> 4, slot = q & 15;
    *(uint4*)(smem + 32768 + ((col * 256 + slot * 16) ^ ((col & 7) << 4))) =
        *(const uint4*)(Wg1T + col * 128 + slot * 8);
  }
  __syncthreads();
  f32x4 acc2g[2][8] = {};
#pragma unroll
  for (int ks = 0; ks < 4; ++ks) {
    int k2 = (ks * 32 + lg * 8) * 2;
    int r0 = wv * 32 + lr;
    bf16x8 a0 = *(const bf16x8*)(smem + ((r0 * 256 + k2) ^ ((r0 & 7) << 4)));
    bf16x8 a1 = *(const bf16x8*)(smem + (((r0 + 16) * 256 + k2) ^ ((r0 & 7) << 4)));
#pragma unroll
    for (int nf = 0; nf < 8; ++nf) {
      int col = nf * 16 + lr;
      bf16x8 b = *(const bf16x8*)(smem + 32768 + ((col * 256 + k2) ^ ((col & 7) << 4)));
      acc2g[0][nf] = MFMA16(a0, b, acc2g[0][nf]);
      acc2g[1][nf] = MFMA16(a1, b, acc2g[1][nf]);
    }
  }

  // ---- combine + LayerNorm + store ----
  float bm1r[8], bg1r[8], gmr[8], btr[8];
#pragma unroll
  for (int nf = 0; nf < 8; ++nf) {
    bm1r[nf] = bm1[nf * 16 + lr];
    bg1r[nf] = bg1[nf * 16 + lr];
    gmr[nf] = gamma[nf * 16 + lr];
    btr[nf] = beta[nf * 16 + lr];
  }
#pragma unroll
  for (int mf = 0; mf < 2; ++mf)
#pragma unroll
    for (int r = 0; r < 4; ++r) {
      int row = wv * 32 + mf * 16 + lg * 4 + r;
      int rg = n0 + row;
      float v[8];
      float s = 0.f, ss = 0.f;
#pragma unroll
      for (int nf = 0; nf < 8; ++nf) {
        float mv = acc2m[mf][nf][r] + bm1r[nf];
        float gv = sigm(acc2g[mf][nf][r] + bg1r[nf]);
        v[nf] = mv * gv;
        s += v[nf];
        ss += v[nf] * v[nf];
      }
#pragma unroll
      for (int msk = 1; msk < 16; msk <<= 1) {
        s += __shfl_xor(s, msk, 64);
        ss += __shfl_xor(ss, msk, 64);
      }
      float mu = s * 0.0078125f;
      float var = ss * 0.0078125f - mu * mu;
      float rs = rsqrtf(var + 1e-5f);
      if (rg < NN) {
#pragma unroll
        for (int nf = 0; nf < 8; ++nf)
          out[(size_t)rg * 128 + nf * 16 + lr] = (v[nf] - mu) * rs * gmr[nf] + btr[nf];
      }
    }
}

extern "C" void kernel_launch(void* const* d_in, const int* in_sizes, int n_in,
                              void* d_out, int out_size, void* d_ws, size_t ws_size,
                              hipStream_t stream) {
  const float* node_inp = (const float*)d_in[0];
  const float* edge_feat = (const float*)d_in[1];
  const float* gstate = (const float*)d_in[2];
  // d_in[3] = cells, unused by reference
  const float* coords = (const float*)d_in[4];
  const int* edge_index = (const int*)d_in[5];
  const float* bWm0 = (const float*)d_in[6];  const float* bbm0 = (const float*)d_in[7];
  const float* bWm1 = (const float*)d_in[8];  const float* bbm1 = (const float*)d_in[9];
  const float* bWg0 = (const float*)d_in[10]; const float* bbg0 = (const float*)d_in[11];
  const float* bWg1 = (const float*)d_in[12]; const float* bbg1 = (const float*)d_in[13];
  const float* nWm0 = (const float*)d_in[14]; const float* nbm0 = (const float*)d_in[15];
  const float* nWm1 = (const float*)d_in[16]; const float* nbm1 = (const float*)d_in[17];
  const float* nWg0 = (const float*)d_in[18]; const float* nbg0 = (const float*)d_in[19];
  const float* nWg1 = (const float*)d_in[20]; const float* nbg1 = (const float*)d_in[21];
  const float* gamma = (const float*)d_in[22]; const float* beta = (const float*)d_in[23];

  char* ws = (char*)d_ws;
  float* sums = (float*)ws;                                 // NN*128 f32 = 25.6e6 B
  float* counts = (float*)(ws + (size_t)NN * 128 * 4);      // NN f32
  size_t woff = (size_t)NN * 128 * 4 + ((NN * 4 + 255) & ~255);
  unsigned short* bWm0T = (unsigned short*)(ws + woff);     // 128*384
  unsigned short* bWg0T = bWm0T + 128 * 384;
  unsigned short* bWm1T = bWg0T + 128 * 384;                // 128*128
  unsigned short* bWg1T = bWm1T + 128 * 128;
  unsigned short* nWm0T = bWg1T + 128 * 128;                // 128*448
  unsigned short* nWg0T = nWm0T + 128 * 448;
  unsigned short* nWm1T = nWg0T + 128 * 448;
  unsigned short* nWg1T = nWm1T + 128 * 128;

  // zero sums+counts every call (atomics accumulate; graph replays don't re-poison)
  hipMemsetAsync(ws, 0, woff, stream);

  // pack weights -> bf16 transposed
  auto packl = [&](const float* W, unsigned short* WT, int K, int Kpad) {
    int total = 128 * Kpad;
    pack_wT<<<(total + 255) / 256, 256, 0, stream>>>(W, WT, K, Kpad);
  };
  packl(bWm0, bWm0T, 384, 384);
  packl(bWg0, bWg0T, 384, 384);
  packl(bWm1, bWm1T, 128, 128);
  packl(bWg1, bWg1T, 128, 128);
  packl(nWm0, nWm0T, 385, 448);
  packl(nWg0, nWg0T, 385, 448);
  packl(nWm1, nWm1T, 128, 128);
  packl(nWg1, nWg1T, 128, 128);

  bond_kernel<<<NE / 128, 256, 0, stream>>>(
      node_inp, edge_feat, edge_index, bWm0T, bWg0T, bWm1T, bWg1T,
      bbm0, bbg0, bbm1, bbg1, sums, counts);

  node_kernel<<<(NN + 127) / 128, 256, 0, stream>>>(
      node_inp, coords, gstate, sums, counts, nWm0T, nWg0T, nWm1T, nWg1T,
      nbm0, nbg0, nbm1, nbg1, gamma, beta, (float*)d_out);
}